// Round 14
// baseline (87.014 us; speedup 1.0000x reference)
//
#include <hip/hip_runtime.h>
#include <stdint.h>

#define BDIM 256
#define TDIM 512           // k_topk block (8 waves)
#define B_   8
#define NCLS 80
#define G_   100
#define N_   33600
#define TOPK_ 13
#define TILES 525          // 400 (level0 20x20) + 100 (level1 10x10) + 25 (level2 5x5), 8x8 anchors each
#define NW   8             // waves per k_topk block
#define CAPC 192           // per-wave cost candidate buffer (u64 keys)
#define CAPI 192           // per-wave iou candidate buffer (f32)
#define NLV  7             // cost probe levels
#define NIV  11            // iou probe levels
#define INFC 1e8f

// ---------- helpers ----------

__device__ __forceinline__ unsigned int fkey(float f){
  unsigned int u = __float_as_uint(f);
  return (u & 0x80000000u) ? ~u : (u | 0x80000000u);  // monotonic float->uint
}
__device__ __forceinline__ float unfkey(unsigned int k){
  unsigned int u = (k & 0x80000000u) ? (k & 0x7fffffffu) : ~k;
  return __uint_as_float(u);
}

// cost = bce*(scale^2) + (-log(iou+eps)*3) + 10^(dist-3); INF-masked by valid
__device__ __forceinline__ float cost_eval(float iou, float x, float dist, bool valid){
  #pragma clang fp contract(off)
  float prior = exp2f((dist - 3.0f) * 3.321928094887362f);   // 10^(dist-3)
  float iouc  = -logf(iou + 1e-7f) * 3.0f;
  float sig   = 1.0f / (1.0f + expf(-x));
  float sc    = iou - sig;
  float bce   = fmaxf(x, 0.0f) + log1pf(expf(-fabsf(x))) - x * iou;
  float c     = bce * (sc * sc) + iouc + prior;
  return valid ? c : INFC;
}

__device__ __forceinline__ unsigned long long wave_min_u64(unsigned long long v){
  #pragma unroll
  for (int m = 1; m < 64; m <<= 1){
    unsigned int lo = (unsigned int)__shfl_xor((int)(unsigned int)v, m, 64);
    unsigned int hi = (unsigned int)__shfl_xor((int)(unsigned int)(v >> 32), m, 64);
    unsigned long long o = ((unsigned long long)hi << 32) | lo;
    v = o < v ? o : v;
  }
  return v;
}

// tile id -> level geometry. Tiles are 8x8 spatial patches; levels: 160x160(s=8), 80x80(s=16), 40x40(s=32).
__device__ __forceinline__ void tile_params(int t, int& W, int& base, int& trow, int& tcol,
                                            float& s, float& invs){
  if (t < 400){            W = 160; base = 0;     s = 8.0f;  invs = 0.125f;
    trow = (t/20)*8;  tcol = (t - (t/20)*20)*8; }
  else if (t < 500){ int u = t - 400; W = 80; base = 25600; s = 16.0f; invs = 0.0625f;
    trow = (u/10)*8; tcol = (u - (u/10)*10)*8; }
  else {             int u = t - 500; W = 40; base = 32000; s = 32.0f; invs = 0.03125f;
    trow = (u/5)*8;  tcol = (u - (u/5)*5)*8; }
}

// exact selection of 13 smallest u64 keys from buf[0..cnt) (cnt<=CAPC). keys unique.
__device__ unsigned long long compact_cost(unsigned long long* buf, int cnt){
  const int lane = threadIdx.x & 63;
  unsigned long long a0 = (lane       < cnt) ? buf[lane]       : ~0ull;
  unsigned long long a1 = (lane + 64  < cnt) ? buf[lane + 64]  : ~0ull;
  unsigned long long a2 = (lane + 128 < cnt) ? buf[lane + 128] : ~0ull;
  unsigned long long mykeep = ~0ull, t13 = ~0ull;
  #pragma unroll
  for (int r = 0; r < TOPK_; ++r){
    unsigned long long v = a0 < a1 ? a0 : a1; v = v < a2 ? v : a2;
    unsigned long long mn = wave_min_u64(v);
    if      (a0 == mn) a0 = ~0ull;
    else if (a1 == mn) a1 = ~0ull;
    else if (a2 == mn) a2 = ~0ull;
    if (lane == r) mykeep = mn;
    t13 = mn;
  }
  if (lane < TOPK_) buf[lane] = mykeep;
  return t13;
}

// exact selection of 13 largest floats (dups allowed) from buf[0..cnt).
__device__ float compact_iou(float* buf, int cnt){
  const int lane = threadIdx.x & 63;
  float a0 = (lane       < cnt) ? buf[lane]       : -1.0f;
  float a1 = (lane + 64  < cnt) ? buf[lane + 64]  : -1.0f;
  float a2 = (lane + 128 < cnt) ? buf[lane + 128] : -1.0f;
  float mykeep = -1.0f, t13 = -1.0f;
  #pragma unroll
  for (int r = 0; r < TOPK_; ++r){
    float mx = fmaxf(fmaxf(a0, a1), a2);
    #pragma unroll
    for (int m = 1; m < 64; m <<= 1) mx = fmaxf(mx, __shfl_xor(mx, m, 64));
    bool h0 = (a0 == mx), h1 = (a1 == mx), h2 = (a2 == mx);
    unsigned long long ball = __ballot(h0 | h1 | h2);
    int src = (int)(__ffsll(ball) - 1);
    if (lane == src){
      if (h0) a0 = -1.0f; else if (h1) a1 = -1.0f; else a2 = -1.0f;
    }
    if (lane == r) mykeep = mx;
    t13 = mx;
  }
  if (lane < TOPK_) buf[lane] = mykeep;
  return t13;
}

// ---------- kernel 0: fused per-tile prep (4 tiles/block): valid bits + zero bitmask + tile aggregates ----------

__global__ void __launch_bounds__(BDIM) k_prep(
    const float* __restrict__ pred_bboxes,
    const float* __restrict__ gt_bboxes,
    const float* __restrict__ pad_flag,
    unsigned char* __restrict__ valid_mask,
    uint32_t* __restrict__ match_mask,
    float4* __restrict__ tile_agg,
    uint32_t* __restrict__ tile_flag)
{
  const int b = blockIdx.y, tid = threadIdx.x, lane = tid & 63, wid = tid >> 6;
  const int t = blockIdx.x*4 + wid;
  __shared__ float4 sbox[G_];
  __shared__ float  sflag[G_];
  for (int g = tid; g < G_; g += BDIM){
    sbox[g]  = ((const float4*)gt_bboxes)[b*G_ + g];
    sflag[g] = pad_flag[b*G_ + g];
  }
  __syncthreads();
  if (t >= TILES) return;

  int W, base, trow, tcol; float s, invs;
  tile_params(t, W, base, trow, tcol, s, invs);
  int row = trow + (lane >> 3), col = tcol + (lane & 7);
  int n = base + row*W + col;
  float cx = ((float)col + 0.5f)*s, cy = ((float)row + 0.5f)*s;   // == priors (exact)

  bool v = false;
  for (int g = 0; g < G_; ++g){
    float4 gb = sbox[g];
    bool in = (cx - gb.x > 0.0f) & (cy - gb.y > 0.0f) &
              (gb.z - cx > 0.0f) & (gb.w - cy > 0.0f) & (sflag[g] > 0.0f);
    v |= in;
  }
  size_t idx = (size_t)b*N_ + n;
  valid_mask[idx] = v ? 1 : 0;
  ((uint4*)match_mask)[idx] = make_uint4(0u,0u,0u,0u);

  float4 pb = ((const float4*)pred_bboxes)[idx];
  float x1 = pb.x, y1 = pb.y, x2 = pb.z, y2 = pb.w;
  #pragma unroll
  for (int m = 1; m < 64; m <<= 1){
    x1 = fminf(x1, __shfl_xor(x1, m, 64));
    y1 = fminf(y1, __shfl_xor(y1, m, 64));
    x2 = fmaxf(x2, __shfl_xor(x2, m, 64));
    y2 = fmaxf(y2, __shfl_xor(y2, m, 64));
  }
  unsigned long long anyb = __ballot(v);
  if (lane == 0){
    tile_agg [(size_t)b*TILES + t] = make_float4(x1, y1, x2, y2);
    tile_flag[(size_t)b*TILES + t] = (anyb != 0ull) ? 1u : 0u;
  }
}

// ---------- kernel 1: per (b,g) tile-pruned top-13 + dyn_k + scatter ----------
// round-robin tile deal (r13) + 1-deep software prefetch of next passing tile's loads

__global__ void __launch_bounds__(TDIM) k_topk(
    const float* __restrict__ pred_bboxes,
    const float* __restrict__ pred_scores,
    const int*   __restrict__ gt_labels,
    const float* __restrict__ gt_bboxes,
    const float* __restrict__ pad_flag,
    const unsigned char* __restrict__ valid_mask,
    const float4* __restrict__ tile_agg,
    const uint32_t* __restrict__ tile_flag,
    uint32_t* __restrict__ match_mask)
{
  #pragma clang fp contract(off)
  const int g = blockIdx.x, b = blockIdx.y;
  if (pad_flag[b*G_ + g] <= 0.0f) return;   // invalid gt: no matches (uniform exit, pre-barrier)

  __shared__ unsigned long long s_cbuf[NW][CAPC];
  __shared__ float s_ibuf[NW][CAPI];
  __shared__ unsigned long long s_fk[NW*TOPK_];
  __shared__ float s_fi[NW*TOPK_];
  __shared__ int s_ccnt[NLV], s_icnt[NIV];
  __shared__ float s_thr[2];

  const int tid = threadIdx.x, lane = tid & 63, wid = tid >> 6;
  unsigned long long* cbuf = s_cbuf[wid];
  float* ibuf = s_ibuf[wid];

  const float4 gb = ((const float4*)gt_bboxes)[b*G_ + g];
  const float ga  = (gb.z - gb.x) * (gb.w - gb.y);
  const float gcx = (gb.x + gb.z) * 0.5f, gcy = (gb.y + gb.w) * 0.5f;
  const int lbl = gt_labels[b*G_ + g];
  const unsigned int KEYINF = fkey(INFC);

  const float4* pb4 = (const float4*)pred_bboxes + (size_t)b*N_;
  const unsigned char* vm = valid_mask + (size_t)b*N_;
  const float* sc_b = pred_scores + (size_t)b*N_*NCLS;
  const float4* tag = tile_agg + (size_t)b*TILES;
  const uint32_t* tfl = tile_flag + (size_t)b*TILES;

  if (tid < NLV) s_ccnt[tid] = 0;
  if (tid < NIV) s_icnt[tid] = 0;
  __syncthreads();

  // ---- seed (distributed over all 8 waves, one round): EXACT costs/ious of 75 patch anchors ----
  {
    auto seed_eval = [&](int t, float& cst, float& iouv){
      #pragma clang fp contract(off)
      int nk, bs; float s, invs;
      if      (t < 25){ nk = 160; bs = 0;     s = 8.0f;  invs = 0.125f;   }
      else if (t < 50){ nk = 80;  bs = 25600; s = 16.0f; invs = 0.0625f;  }
      else            { nk = 40;  bs = 32000; s = 32.0f; invs = 0.03125f; }
      int rem = (t < 25) ? t : ((t < 50) ? t - 25 : t - 50);
      int r = rem / 5, c = rem - 5*r;
      int ix = (int)(gcx / s) - 2, iy = (int)(gcy / s) - 2;
      ix = ix < 0 ? 0 : (ix > nk-5 ? nk-5 : ix);
      iy = iy < 0 ? 0 : (iy > nk-5 ? nk-5 : iy);
      int col = ix + c, row = iy + r;
      int n = bs + row*nk + col;
      float4 pb = pb4[n];
      float pa = (pb.z - pb.x) * (pb.w - pb.y);
      float lx = fmaxf(pb.x, gb.x), ly = fmaxf(pb.y, gb.y);
      float rx = fminf(pb.z, gb.z), ry = fminf(pb.w, gb.w);
      float ov = fmaxf(rx - lx, 0.0f) * fmaxf(ry - ly, 0.0f);
      float un = pa + ga - ov;
      float iou = ov / fmaxf(un, 1e-6f);
      iouv = iou;
      bool valid = vm[n] != 0;
      float px = ((float)col + 0.5f)*s, py = ((float)row + 0.5f)*s;   // == priors (exact)
      float dx = px - gcx, dy = py - gcy;
      float dist = sqrtf(dx*dx + dy*dy) * invs;
      float x = valid ? sc_b[(size_t)n*NCLS + lbl] : 0.0f;
      cst = cost_eval(iou, x, dist, valid);
    };
    float cv = 3e38f, iv = -1.0f;
    int e = wid*10 + lane;
    bool act = (lane < 10) && (e < 75);
    if (act) seed_eval(e, cv, iv);
    const float lvs[NLV] = {47.0f, 24.0f, 12.0f, 6.0f, 3.0f, 1.5f, 0.75f};
    #pragma unroll
    for (int i = 0; i < NLV; ++i){
      int cnt = __popcll(__ballot(act && (cv <= lvs[i])));
      if (lane == 0 && cnt) atomicAdd(&s_ccnt[i], cnt);
    }
    const float ivs[NIV] = {0.002f, 0.005f, 0.01f, 0.02f, 0.05f, 0.1f, 0.15f, 0.22f, 0.3f, 0.4f, 0.5f};
    #pragma unroll
    for (int i = 0; i < NIV; ++i){
      int cnt = __popcll(__ballot(act && (iv >= ivs[i])));
      if (lane == 0 && cnt) atomicAdd(&s_icnt[i], cnt);
    }
  }
  __syncthreads();
  if (tid == 0){
    const float lvs[NLV] = {47.0f, 24.0f, 12.0f, 6.0f, 3.0f, 1.5f, 0.75f};
    const float ivs[NIV] = {0.002f, 0.005f, 0.01f, 0.02f, 0.05f, 0.1f, 0.15f, 0.22f, 0.3f, 0.4f, 0.5f};
    float T = INFC, Ti = 0.0f;
    #pragma unroll
    for (int i = 0; i < NLV; ++i) if (s_ccnt[i] >= TOPK_) T = lvs[i];
    #pragma unroll
    for (int i = 0; i < NIV; ++i) if (s_icnt[i] >= TOPK_) Ti = ivs[i] * 0.999f;
    s_thr[0] = T; s_thr[1] = Ti;
  }
  __syncthreads();

  const float T0 = s_thr[0];
  float Tiou_m = s_thr[1];
  unsigned long long Tkey = ((unsigned long long)fkey(T0) << 32) | 0xFFFFFFFFull;
  bool  tc48  = T0 < 48.0f;
  float gt_   = 3.02f + log10f(T0);
  float gthr2 = gt_ * gt_;                // T0 >= 0.75 -> positive; T0=1e8 -> ~121 (cost>=prior bound)

  int ccnt = 0, icnt = 0;

  // ---- rare: bound is 1e8 -> invalid anchors (cost exactly 1e8, index tie-break) may rank.
  // All waves compute the identical sweep extent (dedup guard); wave 0 stores candidates.
  int sweep_nend = 0;
  if (T0 == INFC){
    int found = 0, base = 0;
    while (found < TOPK_ && base < N_){
      int n = base + lane;
      bool inv = (vm[n] == 0);
      unsigned long long m = __ballot(inv);
      int pc = __popcll(m);
      if (wid == 0){
        int pos = ccnt + (int)__popcll(m & ((1ull << lane) - 1ull));
        if (inv) cbuf[pos] = ((unsigned long long)KEYINF << 32) | (unsigned)n;
        ccnt += pc;                        // bounded: <=76 before first 13 found
      }
      found += pc;
      base += 64;
    }
    sweep_nend = base;                     // wave-uniform across ALL waves
  }

  // ---- tile gating: round-robin deal (tile = wid + 8k), masks kept in registers ----
  unsigned long long pms[2];
  #pragma unroll
  for (int rnd = 0; rnd < 2; ++rnd){
    int tt2 = wid + 8*(rnd*64 + lane);
    bool pass = false;
    if (tt2 < TILES){
      float4 ag = tag[tt2];
      uint32_t fl2 = tfl[tt2];
      int W, bse, trow, tcol; float s, invs;
      tile_params(tt2, W, bse, trow, tcol, s, invs);
      bool inter = (fminf(ag.z, gb.z) > fmaxf(ag.x, gb.x)) &&
                   (fminf(ag.w, gb.w) > fmaxf(ag.y, gb.y));       // some anchor may have ov>0
      float rx0 = ((float)tcol + 0.5f)*s, rx1 = ((float)tcol + 7.5f)*s;
      float ry0 = ((float)trow + 0.5f)*s, ry1 = ((float)trow + 7.5f)*s;
      float ddx = fmaxf(0.0f, fmaxf(rx0 - gcx, gcx - rx1));        // <= per-anchor |dx| (FP-monotone)
      float ddy = fmaxf(0.0f, fmaxf(ry0 - gcy, gcy - ry1));
      float md2s = (ddx*ddx + ddy*ddy) * (invs*invs);
      bool costok = (fl2 != 0) && (md2s <= gthr2) && (inter || !tc48);
      pass = inter || costok;
    }
    pms[rnd] = __ballot(pass);
  }

  // bit iterator over pms[0], pms[1] -> k index (tile = wid + 8k)
  int rsel = 0;
  unsigned long long curm = pms[0];
  auto pop_k = [&]() -> int {
    while (curm == 0ull){
      if (++rsel >= 2) return -1;
      curm = pms[1];
    }
    int bb = (int)(__ffsll(curm) - 1);
    curm &= curm - 1ull;
    return rsel*64 + bb;
  };

  // ---- pipelined tile loop: issue next tile's loads before processing current ----
  int k_cur = pop_k();
  int n_cur = 0; float4 pb_cur = make_float4(0.f,0.f,0.f,0.f); int vm_cur = 0;
  if (k_cur >= 0){
    int tt = wid + 8*k_cur;
    int W, bse, trow, tcol; float s, invs;
    tile_params(tt, W, bse, trow, tcol, s, invs);
    n_cur = bse + (trow + (lane >> 3))*W + tcol + (lane & 7);
    pb_cur = pb4[n_cur];
    vm_cur = vm[n_cur];
  }

  while (k_cur >= 0){
    // prefetch next passing tile (loads overlap current tile's ALU/stream work)
    int k_nxt = pop_k();
    int n_nxt = 0; float4 pb_nxt = pb_cur; int vm_nxt = 0;
    if (k_nxt >= 0){
      int ttn = wid + 8*k_nxt;
      int W2, bse2, trow2, tcol2; float s2, invs2;
      tile_params(ttn, W2, bse2, trow2, tcol2, s2, invs2);
      n_nxt = bse2 + (trow2 + (lane >> 3))*W2 + tcol2 + (lane & 7);
      pb_nxt = pb4[n_nxt];
      vm_nxt = vm[n_nxt];
    }

    // process current tile
    {
      const int tt = wid + 8*k_cur;
      int W, bse, trow, tcol; float s, invs;
      tile_params(tt, W, bse, trow, tcol, s, invs);
      int row = trow + (lane >> 3), col = tcol + (lane & 7);
      const int n = n_cur;
      float px = ((float)col + 0.5f)*s, py = ((float)row + 0.5f)*s;   // == priors (exact)
      float4 pb = pb_cur;
      float pa = (pb.z - pb.x) * (pb.w - pb.y);
      float lx = fmaxf(pb.x, gb.x), ly = fmaxf(pb.y, gb.y);
      float rx = fminf(pb.z, gb.z), ry = fminf(pb.w, gb.w);
      float ov = fmaxf(rx - lx, 0.0f) * fmaxf(ry - ly, 0.0f);
      float un = pa + ga - ov;
      bool ipass = ov > Tiou_m * un;

      float dx = px - gcx, dy = py - gcy;
      float dist2 = dx*dx + dy*dy;
      float d2s = dist2 * (invs * invs);
      bool valid = vm_cur != 0;
      bool needcost = valid && (d2s <= gthr2) && !((ov <= 0.0f) && tc48);

      float iou = 0.0f;
      if (__any(ipass || needcost)){
        if (ipass || needcost) iou = ov / fmaxf(un, 1e-6f);
      }

      // ---- iou top-13 stream ----
      {
        unsigned long long m = __ballot(ipass);
        if (m){
          int pc = __popcll(m);
          if (icnt + pc > CAPI){
            float t = compact_iou(ibuf, icnt); icnt = TOPK_;
            Tiou_m = t * 0.999f;
          }
          int pos = icnt + (int)__popcll(m & ((1ull << lane) - 1ull));
          if (ipass) ibuf[pos] = iou;
          icnt += pc;
        }
      }

      // ---- cost top-13 stream ----
      unsigned long long key = ((unsigned long long)KEYINF << 32) | (unsigned)n;
      bool cpass = (!valid) && (key < Tkey) && (n >= sweep_nend);
      if (__any(needcost)){
        if (needcost){
          float x = sc_b[(size_t)n*NCLS + lbl];
          float dist = sqrtf(dist2) * invs;
          float c = cost_eval(iou, x, dist, true);
          key = ((unsigned long long)fkey(c) << 32) | (unsigned)n;
          cpass = key < Tkey;
        }
      }
      {
        unsigned long long m = __ballot(cpass);
        if (m){
          int pc = __popcll(m);
          if (ccnt + pc > CAPC){
            Tkey = compact_cost(cbuf, ccnt); ccnt = TOPK_;
            float Tc = unfkey((unsigned int)(Tkey >> 32));
            tc48 = Tc < 48.0f;
            float gq = 3.02f + log10f(Tc);
            gthr2 = (gq > 0.0f) ? gq*gq : 1e30f;
          }
          int pos = ccnt + (int)__popcll(m & ((1ull << lane) - 1ull));
          if (cpass) cbuf[pos] = key;
          ccnt += pc;
        }
      }
    }

    k_cur = k_nxt; n_cur = n_nxt; pb_cur = pb_nxt; vm_cur = vm_nxt;
  }

  // ---- per-wave exact selection -> contiguous LDS lists ----
  compact_cost(cbuf, ccnt);
  compact_iou(ibuf, icnt);
  if (lane < TOPK_){ s_fk[wid*TOPK_ + lane] = cbuf[lane]; s_fi[wid*TOPK_ + lane] = ibuf[lane]; }
  __syncthreads();

  // ---- block-level exact selection over 8*13 entries (wave 0) ----
  if (wid == 0){
    compact_cost(s_fk, NW*TOPK_);   // ascending 13 smallest -> s_fk[0..13)
    compact_iou(s_fi, NW*TOPK_);    // descending 13 largest -> s_fi[0..13)
  }
  __syncthreads();

  if (tid == 0){
    float ssum = 0.0f;
    for (int r = 0; r < TOPK_; ++r) ssum += fmaxf(s_fi[r], 0.0f);   // descending order sum
    int dynk = (int)ssum;            // trunc toward zero
    if (dynk < 1) dynk = 1;
    if (dynk > TOPK_) dynk = TOPK_;
    for (int r = 0; r < dynk; ++r){
      int n = (int)(s_fk[r] & 0xffffffffu);
      if (n < N_)                    // insurance vs sentinel pick
        atomicOr(&match_mask[((size_t)b*N_ + n)*4 + (g >> 5)], 1u << (g & 31));
    }
  }
}

// ---------- kernel 2: per (b,n) final assignment ----------
// fast path count<=1; count>1 resolved wave-cooperatively (g across lanes)

__global__ void __launch_bounds__(BDIM) k_assign(
    const float* __restrict__ pred_bboxes,
    const float* __restrict__ pred_scores,
    const float* __restrict__ priors,
    const int*   __restrict__ gt_labels,
    const float* __restrict__ gt_bboxes,
    const unsigned char* __restrict__ valid_mask,
    const uint32_t* __restrict__ match_mask,
    float* __restrict__ out)
{
  #pragma clang fp contract(off)
  const int b = blockIdx.y;
  __shared__ float4 sbox[G_];
  __shared__ int    slbl[G_];
  __shared__ float  sga[G_], sgcx[G_], sgcy[G_];
  for (int g = threadIdx.x; g < G_; g += BDIM){
    float4 q = ((const float4*)gt_bboxes)[b*G_ + g];
    sbox[g] = q; slbl[g] = gt_labels[b*G_ + g];
    sga[g]  = (q.z - q.x) * (q.w - q.y);
    sgcx[g] = (q.x + q.z) * 0.5f;
    sgcy[g] = (q.y + q.w) * 0.5f;
  }
  __syncthreads();
  int n = blockIdx.x*BDIM + threadIdx.x;
  if (n >= N_) return;
  const int lane = threadIdx.x & 63;
  size_t idx = (size_t)b*N_ + n;
  uint4 mm = ((const uint4*)match_mask)[idx];
  int count = __popc(mm.x) + __popc(mm.y) + __popc(mm.z) + __popc(mm.w);

  float lblv = (float)NCLS;
  float4 ob = make_float4(0.f, 0.f, 0.f, 0.f);
  float met = 0.0f;

  if (__any(count > 0)){
    float4 pb = make_float4(0.f,0.f,0.f,0.f); float pa = 0.0f;
    if (count > 0){
      pb = ((const float4*)pred_bboxes)[idx];
      pa = (pb.z - pb.x) * (pb.w - pb.y);
    }
    if (count == 1){
      int mg = mm.x ? (__ffs(mm.x) - 1) :
               mm.y ? (31 + __ffs(mm.y)) :
               mm.z ? (63 + __ffs(mm.z)) : (95 + __ffs(mm.w));
      float4 q = sbox[mg];
      float lx = fmaxf(pb.x, q.x), ly = fmaxf(pb.y, q.y);
      float rx = fminf(pb.z, q.z), ry = fminf(pb.w, q.w);
      float ov = fmaxf(rx - lx, 0.0f) * fmaxf(ry - ly, 0.0f);
      float iou = ov / fmaxf(pa + sga[mg] - ov, 1e-6f);
      lblv = (float)slbl[mg]; ob = q; met = iou;
    }
    unsigned long long heavy = __ballot(count > 1);
    if (heavy){
      float4 pr = make_float4(0.f,0.f,0.f,0.f); int hv0 = 0;
      if (count > 1){
        pr = ((const float4*)priors)[n];
        hv0 = valid_mask[idx];
      }
      while (heavy){
        int src = (int)(__ffsll(heavy) - 1);
        heavy &= heavy - 1ull;
        float hx1 = __shfl(pb.x, src, 64), hy1 = __shfl(pb.y, src, 64);
        float hx2 = __shfl(pb.z, src, 64), hy2 = __shfl(pb.w, src, 64);
        float hpa = __shfl(pa,   src, 64);
        float hcx = __shfl(pr.x, src, 64), hcy = __shfl(pr.y, src, 64);
        float hst = __shfl(pr.z, src, 64);
        int   hv  = __shfl(hv0,  src, 64);
        int   hn  = __shfl(n,    src, 64);
        float hinvs = __uint_as_float(0x7F000000u - __float_as_uint(hst));
        const float* hrow = pred_scores + ((size_t)b*N_ + hn)*(size_t)NCLS;

        unsigned long long bk = ~0ull;
        #pragma unroll
        for (int h = 0; h < 2; ++h){
          int g = lane + h*64;
          if (g < G_){
            float4 q = sbox[g];
            float lx = fmaxf(hx1, q.x), ly = fmaxf(hy1, q.y);
            float rx = fminf(hx2, q.z), ry = fminf(hy2, q.w);
            float ov = fmaxf(rx - lx, 0.0f) * fmaxf(ry - ly, 0.0f);
            float un = hpa + sga[g] - ov;
            float iou = ov / fmaxf(un, 1e-6f);
            float dx = hcx - sgcx[g], dy = hcy - sgcy[g];
            float dist = sqrtf(dx*dx + dy*dy) * hinvs;
            float x = hrow[slbl[g]];
            float c = cost_eval(iou, x, dist, hv != 0);
            unsigned long long key = ((unsigned long long)fkey(c) << 32) | (unsigned)g;
            bk = key < bk ? key : bk;
          }
        }
        bk = wave_min_u64(bk);
        if (lane == src){
          int gw = (int)(bk & 0xffffffffu);
          float4 q = sbox[gw];
          float lx = fmaxf(pb.x, q.x), ly = fmaxf(pb.y, q.y);
          float rx = fminf(pb.z, q.z), ry = fminf(pb.w, q.w);
          float ov = fmaxf(rx - lx, 0.0f) * fmaxf(ry - ly, 0.0f);
          met  = ov / fmaxf(pa + sga[gw] - ov, 1e-6f);
          lblv = (float)slbl[gw];
          ob = q;
        }
      }
    }
  }

  out[idx] = lblv;                                   // assigned_labels
  out[(size_t)B_*N_ + idx] = 1.0f;                   // weights
  ((float4*)(out + (size_t)2*B_*N_))[idx] = ob;      // assigned_bboxes
  out[(size_t)6*B_*N_ + idx] = met;                  // assign_metrics
}

// ---------- launch ----------

extern "C" void kernel_launch(void* const* d_in, const int* in_sizes, int n_in,
                              void* d_out, int out_size, void* d_ws, size_t ws_size,
                              hipStream_t stream) {
  const float* pred_bboxes = (const float*)d_in[0];
  const float* pred_scores = (const float*)d_in[1];
  const float* priors      = (const float*)d_in[2];
  const int*   gt_labels   = (const int*)  d_in[3];
  const float* gt_bboxes   = (const float*)d_in[4];
  const float* pad_flag    = (const float*)d_in[5];
  float* out = (float*)d_out;

  // ws layout: match bitmask | valid mask | tile agg | tile flags
  const size_t MASK_B  = (size_t)B_*N_*4*sizeof(uint32_t);                        // 4,300,800
  const size_t VALID_B = ((size_t)B_*N_ + 255) & ~(size_t)255;                    //   268,800
  const size_t AGG_B   = (size_t)B_*TILES*sizeof(float4);                         //    67,200
  uint32_t* match_mask = (uint32_t*)d_ws;
  unsigned char* valid_mask = (unsigned char*)d_ws + MASK_B;
  float4* tile_agg = (float4*)((char*)d_ws + MASK_B + VALID_B);
  uint32_t* tile_flag = (uint32_t*)((char*)d_ws + MASK_B + VALID_B + AGG_B);

  dim3 gridT((TILES + 3)/4, B_);
  dim3 gridG(G_, B_);
  dim3 gridN((N_ + BDIM - 1)/BDIM, B_);

  k_prep<<<gridT, BDIM, 0, stream>>>(pred_bboxes, gt_bboxes, pad_flag,
                                     valid_mask, match_mask, tile_agg, tile_flag);
  k_topk<<<gridG, TDIM, 0, stream>>>(pred_bboxes, pred_scores, gt_labels,
                                     gt_bboxes, pad_flag, valid_mask,
                                     tile_agg, tile_flag, match_mask);
  k_assign<<<gridN, BDIM, 0, stream>>>(pred_bboxes, pred_scores, priors, gt_labels,
                                       gt_bboxes, valid_mask, match_mask, out);
}

// Round 15
// 69.018 us; speedup vs baseline: 1.2608x; 1.2608x over previous
//
#include <hip/hip_runtime.h>
#include <stdint.h>

#define BDIM 256
#define TDIM 512           // k_topk block (8 waves)
#define B_   8
#define NCLS 80
#define G_   100
#define N_   33600
#define TOPK_ 13
#define TILES 525          // 400 (level0 20x20) + 100 (level1 10x10) + 25 (level2 5x5), 8x8 anchors each
#define NW   8             // waves per k_topk block
#define CAPC 160           // per-wave cost candidate buffer (u64 keys)
#define CAPI 160           // per-wave iou candidate buffer (f32)
#define NLV  7             // cost probe levels
#define NIV  11            // iou probe levels
#define INFC 1e8f

// ---------- helpers ----------

__device__ __forceinline__ unsigned int fkey(float f){
  unsigned int u = __float_as_uint(f);
  return (u & 0x80000000u) ? ~u : (u | 0x80000000u);  // monotonic float->uint
}
__device__ __forceinline__ float unfkey(unsigned int k){
  unsigned int u = (k & 0x80000000u) ? (k & 0x7fffffffu) : ~k;
  return __uint_as_float(u);
}

// cost = bce*(scale^2) + (-log(iou+eps)*3) + 10^(dist-3); INF-masked by valid
__device__ __forceinline__ float cost_eval(float iou, float x, float dist, bool valid){
  #pragma clang fp contract(off)
  float prior = exp2f((dist - 3.0f) * 3.321928094887362f);   // 10^(dist-3)
  float iouc  = -logf(iou + 1e-7f) * 3.0f;
  float sig   = 1.0f / (1.0f + expf(-x));
  float sc    = iou - sig;
  float bce   = fmaxf(x, 0.0f) + log1pf(expf(-fabsf(x))) - x * iou;
  float c     = bce * (sc * sc) + iouc + prior;
  return valid ? c : INFC;
}

__device__ __forceinline__ unsigned long long wave_min_u64(unsigned long long v){
  #pragma unroll
  for (int m = 1; m < 64; m <<= 1){
    unsigned int lo = (unsigned int)__shfl_xor((int)(unsigned int)v, m, 64);
    unsigned int hi = (unsigned int)__shfl_xor((int)(unsigned int)(v >> 32), m, 64);
    unsigned long long o = ((unsigned long long)hi << 32) | lo;
    v = o < v ? o : v;
  }
  return v;
}

// tile id -> level geometry. Tiles are 8x8 spatial patches; levels: 160x160(s=8), 80x80(s=16), 40x40(s=32).
__device__ __forceinline__ void tile_params(int t, int& W, int& base, int& trow, int& tcol,
                                            float& s, float& invs){
  if (t < 400){            W = 160; base = 0;     s = 8.0f;  invs = 0.125f;
    trow = (t/20)*8;  tcol = (t - (t/20)*20)*8; }
  else if (t < 500){ int u = t - 400; W = 80; base = 25600; s = 16.0f; invs = 0.0625f;
    trow = (u/10)*8; tcol = (u - (u/10)*10)*8; }
  else {             int u = t - 500; W = 40; base = 32000; s = 32.0f; invs = 0.03125f;
    trow = (u/5)*8;  tcol = (u - (u/5)*5)*8; }
}

// exact selection of 13 smallest u64 keys from buf[0..cnt) (cnt<=CAPC). keys unique.
__device__ unsigned long long compact_cost(unsigned long long* buf, int cnt){
  const int lane = threadIdx.x & 63;
  unsigned long long a0 = (lane       < cnt) ? buf[lane]       : ~0ull;
  unsigned long long a1 = (lane + 64  < cnt) ? buf[lane + 64]  : ~0ull;
  unsigned long long a2 = (lane + 128 < cnt) ? buf[lane + 128] : ~0ull;
  unsigned long long mykeep = ~0ull, t13 = ~0ull;
  #pragma unroll
  for (int r = 0; r < TOPK_; ++r){
    unsigned long long v = a0 < a1 ? a0 : a1; v = v < a2 ? v : a2;
    unsigned long long mn = wave_min_u64(v);
    if      (a0 == mn) a0 = ~0ull;
    else if (a1 == mn) a1 = ~0ull;
    else if (a2 == mn) a2 = ~0ull;
    if (lane == r) mykeep = mn;
    t13 = mn;
  }
  if (lane < TOPK_) buf[lane] = mykeep;
  return t13;
}

// exact selection of 13 largest floats (dups allowed) from buf[0..cnt).
__device__ float compact_iou(float* buf, int cnt){
  const int lane = threadIdx.x & 63;
  float a0 = (lane       < cnt) ? buf[lane]       : -1.0f;
  float a1 = (lane + 64  < cnt) ? buf[lane + 64]  : -1.0f;
  float a2 = (lane + 128 < cnt) ? buf[lane + 128] : -1.0f;
  float mykeep = -1.0f, t13 = -1.0f;
  #pragma unroll
  for (int r = 0; r < TOPK_; ++r){
    float mx = fmaxf(fmaxf(a0, a1), a2);
    #pragma unroll
    for (int m = 1; m < 64; m <<= 1) mx = fmaxf(mx, __shfl_xor(mx, m, 64));
    bool h0 = (a0 == mx), h1 = (a1 == mx), h2 = (a2 == mx);
    unsigned long long ball = __ballot(h0 | h1 | h2);
    int src = (int)(__ffsll(ball) - 1);
    if (lane == src){
      if (h0) a0 = -1.0f; else if (h1) a1 = -1.0f; else a2 = -1.0f;
    }
    if (lane == r) mykeep = mx;
    t13 = mx;
  }
  if (lane < TOPK_) buf[lane] = mykeep;
  return t13;
}

// ---------- kernel 0: fused per-tile prep (4 tiles/block): valid bits + zero bitmask + tile aggregates ----------

__global__ void __launch_bounds__(BDIM) k_prep(
    const float* __restrict__ pred_bboxes,
    const float* __restrict__ gt_bboxes,
    const float* __restrict__ pad_flag,
    unsigned char* __restrict__ valid_mask,
    uint32_t* __restrict__ match_mask,
    float4* __restrict__ tile_agg,
    uint32_t* __restrict__ tile_flag)
{
  const int b = blockIdx.y, tid = threadIdx.x, lane = tid & 63, wid = tid >> 6;
  const int t = blockIdx.x*4 + wid;
  __shared__ float4 sbox[G_];
  __shared__ float  sflag[G_];
  for (int g = tid; g < G_; g += BDIM){
    sbox[g]  = ((const float4*)gt_bboxes)[b*G_ + g];
    sflag[g] = pad_flag[b*G_ + g];
  }
  __syncthreads();
  if (t >= TILES) return;

  int W, base, trow, tcol; float s, invs;
  tile_params(t, W, base, trow, tcol, s, invs);
  int row = trow + (lane >> 3), col = tcol + (lane & 7);
  int n = base + row*W + col;
  float cx = ((float)col + 0.5f)*s, cy = ((float)row + 0.5f)*s;   // == priors (exact)

  bool v = false;
  for (int g = 0; g < G_; ++g){
    float4 gb = sbox[g];
    bool in = (cx - gb.x > 0.0f) & (cy - gb.y > 0.0f) &
              (gb.z - cx > 0.0f) & (gb.w - cy > 0.0f) & (sflag[g] > 0.0f);
    v |= in;
  }
  size_t idx = (size_t)b*N_ + n;
  valid_mask[idx] = v ? 1 : 0;
  ((uint4*)match_mask)[idx] = make_uint4(0u,0u,0u,0u);

  float4 pb = ((const float4*)pred_bboxes)[idx];
  float x1 = pb.x, y1 = pb.y, x2 = pb.z, y2 = pb.w;
  #pragma unroll
  for (int m = 1; m < 64; m <<= 1){
    x1 = fminf(x1, __shfl_xor(x1, m, 64));
    y1 = fminf(y1, __shfl_xor(y1, m, 64));
    x2 = fmaxf(x2, __shfl_xor(x2, m, 64));
    y2 = fmaxf(y2, __shfl_xor(y2, m, 64));
  }
  unsigned long long anyb = __ballot(v);
  if (lane == 0){
    tile_agg [(size_t)b*TILES + t] = make_float4(x1, y1, x2, y2);
    tile_flag[(size_t)b*TILES + t] = (anyb != 0ull) ? 1u : 0u;
  }
}

// ---------- kernel 1: per (b,g) tile-pruned top-13 + dyn_k + scatter ----------
// r13 structure (round-robin deal); iou tile gate tightened from "union bbox
// intersects gt" to the quantitative bound uov > Tiou_m * ga * 0.999.

__global__ void __launch_bounds__(TDIM) k_topk(
    const float* __restrict__ pred_bboxes,
    const float* __restrict__ pred_scores,
    const int*   __restrict__ gt_labels,
    const float* __restrict__ gt_bboxes,
    const float* __restrict__ pad_flag,
    const unsigned char* __restrict__ valid_mask,
    const float4* __restrict__ tile_agg,
    const uint32_t* __restrict__ tile_flag,
    uint32_t* __restrict__ match_mask)
{
  #pragma clang fp contract(off)
  const int g = blockIdx.x, b = blockIdx.y;
  if (pad_flag[b*G_ + g] <= 0.0f) return;   // invalid gt: no matches (uniform exit, pre-barrier)

  __shared__ unsigned long long s_cbuf[NW][CAPC];
  __shared__ float s_ibuf[NW][CAPI];
  __shared__ unsigned long long s_fk[NW*TOPK_];
  __shared__ float s_fi[NW*TOPK_];
  __shared__ int s_ccnt[NLV], s_icnt[NIV];
  __shared__ float s_thr[2];

  const int tid = threadIdx.x, lane = tid & 63, wid = tid >> 6;
  unsigned long long* cbuf = s_cbuf[wid];
  float* ibuf = s_ibuf[wid];

  const float4 gb = ((const float4*)gt_bboxes)[b*G_ + g];
  const float ga  = (gb.z - gb.x) * (gb.w - gb.y);
  const float gcx = (gb.x + gb.z) * 0.5f, gcy = (gb.y + gb.w) * 0.5f;
  const int lbl = gt_labels[b*G_ + g];
  const unsigned int KEYINF = fkey(INFC);

  const float4* pb4 = (const float4*)pred_bboxes + (size_t)b*N_;
  const unsigned char* vm = valid_mask + (size_t)b*N_;
  const float* sc_b = pred_scores + (size_t)b*N_*NCLS;
  const float4* tag = tile_agg + (size_t)b*TILES;
  const uint32_t* tfl = tile_flag + (size_t)b*TILES;

  if (tid < NLV) s_ccnt[tid] = 0;
  if (tid < NIV) s_icnt[tid] = 0;
  __syncthreads();

  // ---- seed (distributed over all 8 waves, one round): EXACT costs/ious of 75 patch anchors ----
  {
    auto seed_eval = [&](int t, float& cst, float& iouv){
      #pragma clang fp contract(off)
      int nk, bs; float s, invs;
      if      (t < 25){ nk = 160; bs = 0;     s = 8.0f;  invs = 0.125f;   }
      else if (t < 50){ nk = 80;  bs = 25600; s = 16.0f; invs = 0.0625f;  }
      else            { nk = 40;  bs = 32000; s = 32.0f; invs = 0.03125f; }
      int rem = (t < 25) ? t : ((t < 50) ? t - 25 : t - 50);
      int r = rem / 5, c = rem - 5*r;
      int ix = (int)(gcx / s) - 2, iy = (int)(gcy / s) - 2;
      ix = ix < 0 ? 0 : (ix > nk-5 ? nk-5 : ix);
      iy = iy < 0 ? 0 : (iy > nk-5 ? nk-5 : iy);
      int col = ix + c, row = iy + r;
      int n = bs + row*nk + col;
      float4 pb = pb4[n];
      float pa = (pb.z - pb.x) * (pb.w - pb.y);
      float lx = fmaxf(pb.x, gb.x), ly = fmaxf(pb.y, gb.y);
      float rx = fminf(pb.z, gb.z), ry = fminf(pb.w, gb.w);
      float ov = fmaxf(rx - lx, 0.0f) * fmaxf(ry - ly, 0.0f);
      float un = pa + ga - ov;
      float iou = ov / fmaxf(un, 1e-6f);
      iouv = iou;
      bool valid = vm[n] != 0;
      float px = ((float)col + 0.5f)*s, py = ((float)row + 0.5f)*s;   // == priors (exact)
      float dx = px - gcx, dy = py - gcy;
      float dist = sqrtf(dx*dx + dy*dy) * invs;
      float x = valid ? sc_b[(size_t)n*NCLS + lbl] : 0.0f;
      cst = cost_eval(iou, x, dist, valid);
    };
    float cv = 3e38f, iv = -1.0f;
    int e = wid*10 + lane;
    bool act = (lane < 10) && (e < 75);
    if (act) seed_eval(e, cv, iv);
    const float lvs[NLV] = {47.0f, 24.0f, 12.0f, 6.0f, 3.0f, 1.5f, 0.75f};
    #pragma unroll
    for (int i = 0; i < NLV; ++i){
      int cnt = __popcll(__ballot(act && (cv <= lvs[i])));
      if (lane == 0 && cnt) atomicAdd(&s_ccnt[i], cnt);
    }
    const float ivs[NIV] = {0.002f, 0.005f, 0.01f, 0.02f, 0.05f, 0.1f, 0.15f, 0.22f, 0.3f, 0.4f, 0.5f};
    #pragma unroll
    for (int i = 0; i < NIV; ++i){
      int cnt = __popcll(__ballot(act && (iv >= ivs[i])));
      if (lane == 0 && cnt) atomicAdd(&s_icnt[i], cnt);
    }
  }
  __syncthreads();
  if (tid == 0){
    const float lvs[NLV] = {47.0f, 24.0f, 12.0f, 6.0f, 3.0f, 1.5f, 0.75f};
    const float ivs[NIV] = {0.002f, 0.005f, 0.01f, 0.02f, 0.05f, 0.1f, 0.15f, 0.22f, 0.3f, 0.4f, 0.5f};
    float T = INFC, Ti = 0.0f;
    #pragma unroll
    for (int i = 0; i < NLV; ++i) if (s_ccnt[i] >= TOPK_) T = lvs[i];
    #pragma unroll
    for (int i = 0; i < NIV; ++i) if (s_icnt[i] >= TOPK_) Ti = ivs[i] * 0.999f;
    s_thr[0] = T; s_thr[1] = Ti;
  }
  __syncthreads();

  const float T0 = s_thr[0];
  float Tiou_m = s_thr[1];
  const float Tiou_gate = Tiou_m * ga * 0.999f;   // tile-level iou bound (conservative)
  unsigned long long Tkey = ((unsigned long long)fkey(T0) << 32) | 0xFFFFFFFFull;
  bool  tc48  = T0 < 48.0f;
  float gt_   = 3.02f + log10f(T0);
  float gthr2 = gt_ * gt_;                // T0 >= 0.75 -> positive; T0=1e8 -> ~121 (cost>=prior bound)

  int ccnt = 0, icnt = 0;

  // ---- rare: bound is 1e8 -> invalid anchors (cost exactly 1e8, index tie-break) may rank.
  // All waves compute the identical sweep extent (dedup guard); wave 0 stores candidates.
  int sweep_nend = 0;
  if (T0 == INFC){
    int found = 0, base = 0;
    while (found < TOPK_ && base < N_){
      int n = base + lane;
      bool inv = (vm[n] == 0);
      unsigned long long m = __ballot(inv);
      int pc = __popcll(m);
      if (wid == 0){
        int pos = ccnt + (int)__popcll(m & ((1ull << lane) - 1ull));
        if (inv) cbuf[pos] = ((unsigned long long)KEYINF << 32) | (unsigned)n;
        ccnt += pc;                        // bounded: <=76 before first 13 found
      }
      found += pc;
      base += 64;
    }
    sweep_nend = base;                     // wave-uniform across ALL waves
  }

  // ---- tile loop: round-robin deal (tile = wid + 8k), 2 rounds of 64 strided tiles ----
  #pragma unroll
  for (int rnd = 0; rnd < 2; ++rnd){
    int tt2 = wid + 8*(rnd*64 + lane);
    bool pass = false;
    if (tt2 < TILES){
      float4 ag = tag[tt2];
      uint32_t fl2 = tfl[tt2];
      int W, bse, trow, tcol; float s, invs;
      tile_params(tt2, W, bse, trow, tcol, s, invs);
      float ow = fmaxf(fminf(ag.z, gb.z) - fmaxf(ag.x, gb.x), 0.0f);
      float oh = fmaxf(fminf(ag.w, gb.w) - fmaxf(ag.y, gb.y), 0.0f);
      float uov = ow * oh;                                         // >= any anchor's ov (FP-monotone)
      bool inter = uov > 0.0f;
      bool ioucand = uov > Tiou_gate;                              // tile can hold iou > Tiou
      float rx0 = ((float)tcol + 0.5f)*s, rx1 = ((float)tcol + 7.5f)*s;
      float ry0 = ((float)trow + 0.5f)*s, ry1 = ((float)trow + 7.5f)*s;
      float ddx = fmaxf(0.0f, fmaxf(rx0 - gcx, gcx - rx1));        // <= per-anchor |dx| (FP-monotone)
      float ddy = fmaxf(0.0f, fmaxf(ry0 - gcy, gcy - ry1));
      float md2s = (ddx*ddx + ddy*ddy) * (invs*invs);
      bool costok = (fl2 != 0) && (md2s <= gthr2) && (inter || !tc48);
      pass = ioucand || costok;
    }
    unsigned long long pm = __ballot(pass);
    while (pm){
      int bit = (int)(__ffsll(pm) - 1);
      pm &= pm - 1ull;
      const int tt = wid + 8*(rnd*64 + bit);        // wave-uniform tile

      int W, bse, trow, tcol; float s, invs;
      tile_params(tt, W, bse, trow, tcol, s, invs);
      int row = trow + (lane >> 3), col = tcol + (lane & 7);
      int n = bse + row*W + col;
      float px = ((float)col + 0.5f)*s, py = ((float)row + 0.5f)*s;   // == priors (exact)
      float4 pb = pb4[n];
      float pa = (pb.z - pb.x) * (pb.w - pb.y);
      float lx = fmaxf(pb.x, gb.x), ly = fmaxf(pb.y, gb.y);
      float rx = fminf(pb.z, gb.z), ry = fminf(pb.w, gb.w);
      float ov = fmaxf(rx - lx, 0.0f) * fmaxf(ry - ly, 0.0f);
      float un = pa + ga - ov;
      bool ipass = ov > Tiou_m * un;

      float dx = px - gcx, dy = py - gcy;
      float dist2 = dx*dx + dy*dy;
      float d2s = dist2 * (invs * invs);
      bool valid = vm[n] != 0;
      bool needcost = valid && (d2s <= gthr2) && !((ov <= 0.0f) && tc48);

      float iou = 0.0f;
      if (__any(ipass || needcost)){
        if (ipass || needcost) iou = ov / fmaxf(un, 1e-6f);
      }

      // ---- iou top-13 stream ----
      {
        unsigned long long m = __ballot(ipass);
        if (m){
          int pc = __popcll(m);
          if (icnt + pc > CAPI){
            float t = compact_iou(ibuf, icnt); icnt = TOPK_;
            Tiou_m = t * 0.999f;
          }
          int pos = icnt + (int)__popcll(m & ((1ull << lane) - 1ull));
          if (ipass) ibuf[pos] = iou;
          icnt += pc;
        }
      }

      // ---- cost top-13 stream ----
      unsigned long long key = ((unsigned long long)KEYINF << 32) | (unsigned)n;
      bool cpass = (!valid) && (key < Tkey) && (n >= sweep_nend);
      if (__any(needcost)){
        if (needcost){
          float x = sc_b[(size_t)n*NCLS + lbl];
          float dist = sqrtf(dist2) * invs;
          float c = cost_eval(iou, x, dist, true);
          key = ((unsigned long long)fkey(c) << 32) | (unsigned)n;
          cpass = key < Tkey;
        }
      }
      {
        unsigned long long m = __ballot(cpass);
        if (m){
          int pc = __popcll(m);
          if (ccnt + pc > CAPC){
            Tkey = compact_cost(cbuf, ccnt); ccnt = TOPK_;
            float Tc = unfkey((unsigned int)(Tkey >> 32));
            tc48 = Tc < 48.0f;
            float gq = 3.02f + log10f(Tc);
            gthr2 = (gq > 0.0f) ? gq*gq : 1e30f;
          }
          int pos = ccnt + (int)__popcll(m & ((1ull << lane) - 1ull));
          if (cpass) cbuf[pos] = key;
          ccnt += pc;
        }
      }
    }
  }

  // ---- per-wave exact selection -> contiguous LDS lists ----
  compact_cost(cbuf, ccnt);
  compact_iou(ibuf, icnt);
  if (lane < TOPK_){ s_fk[wid*TOPK_ + lane] = cbuf[lane]; s_fi[wid*TOPK_ + lane] = ibuf[lane]; }
  __syncthreads();

  // ---- block-level exact selection over 8*13 entries (wave 0) ----
  if (wid == 0){
    compact_cost(s_fk, NW*TOPK_);   // ascending 13 smallest -> s_fk[0..13)
    compact_iou(s_fi, NW*TOPK_);    // descending 13 largest -> s_fi[0..13)
  }
  __syncthreads();

  if (tid == 0){
    float ssum = 0.0f;
    for (int r = 0; r < TOPK_; ++r) ssum += fmaxf(s_fi[r], 0.0f);   // descending order sum
    int dynk = (int)ssum;            // trunc toward zero
    if (dynk < 1) dynk = 1;
    if (dynk > TOPK_) dynk = TOPK_;
    for (int r = 0; r < dynk; ++r){
      int n = (int)(s_fk[r] & 0xffffffffu);
      if (n < N_)                    // insurance vs sentinel pick
        atomicOr(&match_mask[((size_t)b*N_ + n)*4 + (g >> 5)], 1u << (g & 31));
    }
  }
}

// ---------- kernel 2: per (b,n) final assignment ----------
// fast path count<=1; count>1 resolved wave-cooperatively (g across lanes)

__global__ void __launch_bounds__(BDIM) k_assign(
    const float* __restrict__ pred_bboxes,
    const float* __restrict__ pred_scores,
    const float* __restrict__ priors,
    const int*   __restrict__ gt_labels,
    const float* __restrict__ gt_bboxes,
    const unsigned char* __restrict__ valid_mask,
    const uint32_t* __restrict__ match_mask,
    float* __restrict__ out)
{
  #pragma clang fp contract(off)
  const int b = blockIdx.y;
  __shared__ float4 sbox[G_];
  __shared__ int    slbl[G_];
  __shared__ float  sga[G_], sgcx[G_], sgcy[G_];
  for (int g = threadIdx.x; g < G_; g += BDIM){
    float4 q = ((const float4*)gt_bboxes)[b*G_ + g];
    sbox[g] = q; slbl[g] = gt_labels[b*G_ + g];
    sga[g]  = (q.z - q.x) * (q.w - q.y);
    sgcx[g] = (q.x + q.z) * 0.5f;
    sgcy[g] = (q.y + q.w) * 0.5f;
  }
  __syncthreads();
  int n = blockIdx.x*BDIM + threadIdx.x;
  if (n >= N_) return;
  const int lane = threadIdx.x & 63;
  size_t idx = (size_t)b*N_ + n;
  uint4 mm = ((const uint4*)match_mask)[idx];
  int count = __popc(mm.x) + __popc(mm.y) + __popc(mm.z) + __popc(mm.w);

  float lblv = (float)NCLS;
  float4 ob = make_float4(0.f, 0.f, 0.f, 0.f);
  float met = 0.0f;

  if (__any(count > 0)){
    float4 pb = make_float4(0.f,0.f,0.f,0.f); float pa = 0.0f;
    if (count > 0){
      pb = ((const float4*)pred_bboxes)[idx];
      pa = (pb.z - pb.x) * (pb.w - pb.y);
    }
    if (count == 1){
      int mg = mm.x ? (__ffs(mm.x) - 1) :
               mm.y ? (31 + __ffs(mm.y)) :
               mm.z ? (63 + __ffs(mm.z)) : (95 + __ffs(mm.w));
      float4 q = sbox[mg];
      float lx = fmaxf(pb.x, q.x), ly = fmaxf(pb.y, q.y);
      float rx = fminf(pb.z, q.z), ry = fminf(pb.w, q.w);
      float ov = fmaxf(rx - lx, 0.0f) * fmaxf(ry - ly, 0.0f);
      float iou = ov / fmaxf(pa + sga[mg] - ov, 1e-6f);
      lblv = (float)slbl[mg]; ob = q; met = iou;
    }
    unsigned long long heavy = __ballot(count > 1);
    if (heavy){
      float4 pr = make_float4(0.f,0.f,0.f,0.f); int hv0 = 0;
      if (count > 1){
        pr = ((const float4*)priors)[n];
        hv0 = valid_mask[idx];
      }
      while (heavy){
        int src = (int)(__ffsll(heavy) - 1);
        heavy &= heavy - 1ull;
        float hx1 = __shfl(pb.x, src, 64), hy1 = __shfl(pb.y, src, 64);
        float hx2 = __shfl(pb.z, src, 64), hy2 = __shfl(pb.w, src, 64);
        float hpa = __shfl(pa,   src, 64);
        float hcx = __shfl(pr.x, src, 64), hcy = __shfl(pr.y, src, 64);
        float hst = __shfl(pr.z, src, 64);
        int   hv  = __shfl(hv0,  src, 64);
        int   hn  = __shfl(n,    src, 64);
        float hinvs = __uint_as_float(0x7F000000u - __float_as_uint(hst));
        const float* hrow = pred_scores + ((size_t)b*N_ + hn)*(size_t)NCLS;

        unsigned long long bk = ~0ull;
        #pragma unroll
        for (int h = 0; h < 2; ++h){
          int g = lane + h*64;
          if (g < G_){
            float4 q = sbox[g];
            float lx = fmaxf(hx1, q.x), ly = fmaxf(hy1, q.y);
            float rx = fminf(hx2, q.z), ry = fminf(hy2, q.w);
            float ov = fmaxf(rx - lx, 0.0f) * fmaxf(ry - ly, 0.0f);
            float un = hpa + sga[g] - ov;
            float iou = ov / fmaxf(un, 1e-6f);
            float dx = hcx - sgcx[g], dy = hcy - sgcy[g];
            float dist = sqrtf(dx*dx + dy*dy) * hinvs;
            float x = hrow[slbl[g]];
            float c = cost_eval(iou, x, dist, hv != 0);
            unsigned long long key = ((unsigned long long)fkey(c) << 32) | (unsigned)g;
            bk = key < bk ? key : bk;
          }
        }
        bk = wave_min_u64(bk);
        if (lane == src){
          int gw = (int)(bk & 0xffffffffu);
          float4 q = sbox[gw];
          float lx = fmaxf(pb.x, q.x), ly = fmaxf(pb.y, q.y);
          float rx = fminf(pb.z, q.z), ry = fminf(pb.w, q.w);
          float ov = fmaxf(rx - lx, 0.0f) * fmaxf(ry - ly, 0.0f);
          met  = ov / fmaxf(pa + sga[gw] - ov, 1e-6f);
          lblv = (float)slbl[gw];
          ob = q;
        }
      }
    }
  }

  out[idx] = lblv;                                   // assigned_labels
  out[(size_t)B_*N_ + idx] = 1.0f;                   // weights
  ((float4*)(out + (size_t)2*B_*N_))[idx] = ob;      // assigned_bboxes
  out[(size_t)6*B_*N_ + idx] = met;                  // assign_metrics
}

// ---------- launch ----------

extern "C" void kernel_launch(void* const* d_in, const int* in_sizes, int n_in,
                              void* d_out, int out_size, void* d_ws, size_t ws_size,
                              hipStream_t stream) {
  const float* pred_bboxes = (const float*)d_in[0];
  const float* pred_scores = (const float*)d_in[1];
  const float* priors      = (const float*)d_in[2];
  const int*   gt_labels   = (const int*)  d_in[3];
  const float* gt_bboxes   = (const float*)d_in[4];
  const float* pad_flag    = (const float*)d_in[5];
  float* out = (float*)d_out;

  // ws layout: match bitmask | valid mask | tile agg | tile flags
  const size_t MASK_B  = (size_t)B_*N_*4*sizeof(uint32_t);                        // 4,300,800
  const size_t VALID_B = ((size_t)B_*N_ + 255) & ~(size_t)255;                    //   268,800
  const size_t AGG_B   = (size_t)B_*TILES*sizeof(float4);                         //    67,200
  uint32_t* match_mask = (uint32_t*)d_ws;
  unsigned char* valid_mask = (unsigned char*)d_ws + MASK_B;
  float4* tile_agg = (float4*)((char*)d_ws + MASK_B + VALID_B);
  uint32_t* tile_flag = (uint32_t*)((char*)d_ws + MASK_B + VALID_B + AGG_B);

  dim3 gridT((TILES + 3)/4, B_);
  dim3 gridG(G_, B_);
  dim3 gridN((N_ + BDIM - 1)/BDIM, B_);

  k_prep<<<gridT, BDIM, 0, stream>>>(pred_bboxes, gt_bboxes, pad_flag,
                                     valid_mask, match_mask, tile_agg, tile_flag);
  k_topk<<<gridG, TDIM, 0, stream>>>(pred_bboxes, pred_scores, gt_labels,
                                     gt_bboxes, pad_flag, valid_mask,
                                     tile_agg, tile_flag, match_mask);
  k_assign<<<gridN, BDIM, 0, stream>>>(pred_bboxes, pred_scores, priors, gt_labels,
                                       gt_bboxes, valid_mask, match_mask, out);
}